// Round 1
// baseline (656.195 us; speedup 1.0000x reference)
//
#include <hip/hip_runtime.h>

#define NN 20000      // nodes
#define NE 640000     // edges (without self loops)
#define NEE 660000    // edges + self loops
#define NP 200000     // drug pairs
#define NEG 0.2f      // leaky relu slope

// ---------------- CSR build ----------------
__global__ void k_hist(const int* __restrict__ ei, int* __restrict__ cnt) {
  int i = blockIdx.x * 256 + threadIdx.x;
  if (i >= NEE) return;
  int d = (i < NE) ? ei[NE + i] : (i - NE);
  atomicAdd(&cnt[d], 1);
}

__global__ void k_scan(const int* __restrict__ cnt, int* __restrict__ rp) {
  __shared__ int ps[256];
  const int CH = 79;  // 79*256 = 20224 >= 20000
  int t = threadIdx.x;
  int lo = t * CH, hi = lo + CH;
  if (hi > NN) hi = NN;
  if (lo > NN) lo = NN;
  int s = 0;
  for (int i = lo; i < hi; ++i) s += cnt[i];
  ps[t] = s;
  __syncthreads();
  for (int off = 1; off < 256; off <<= 1) {
    int v = (t >= off) ? ps[t - off] : 0;
    __syncthreads();
    ps[t] += v;
    __syncthreads();
  }
  int run = (t > 0) ? ps[t - 1] : 0;
  for (int i = lo; i < hi; ++i) { rp[i] = run; run += cnt[i]; }
  if (t == 255) rp[NN] = ps[255];
}

__global__ void k_scatter(const int* __restrict__ ei, const int* __restrict__ rp,
                          int* __restrict__ cur, int* __restrict__ col) {
  int i = blockIdx.x * 256 + threadIdx.x;
  if (i >= NEE) return;
  int s, d;
  if (i < NE) { s = ei[i]; d = ei[NE + i]; } else { s = i - NE; d = s; }
  int pos = atomicAdd(&cur[d], 1);
  col[rp[d] + pos] = s;
}

// ---------------- GEMM1: h1 = x @ W1  [20000,256]x[256,256], + alphas ----------------
__global__ __launch_bounds__(256) void k_gemm1(
    const float* __restrict__ x, const float* __restrict__ W1,
    const float* __restrict__ as1, const float* __restrict__ ad1,
    float* __restrict__ h1, float* __restrict__ AS1, float* __restrict__ AD1) {
  __shared__ float xsT[256][20];  // [k][row], pad 20 keeps 16B row alignment
  int c = threadIdx.x;            // output col 0..255
  int base = blockIdx.x * 16;     // 16 rows per block
  for (int i = threadIdx.x; i < 16 * 256; i += 256) {
    int r = i >> 8, k = i & 255;
    xsT[k][r] = x[(base + r) * 256 + k];
  }
  __syncthreads();
  float acc[16];
#pragma unroll
  for (int r = 0; r < 16; ++r) acc[r] = 0.f;
#pragma unroll 2
  for (int k = 0; k < 256; ++k) {
    float wv = W1[k * 256 + c];
    const float4* xr = (const float4*)&xsT[k][0];
    float4 x0 = xr[0], x1 = xr[1], x2 = xr[2], x3 = xr[3];
    acc[0] += x0.x * wv; acc[1] += x0.y * wv; acc[2] += x0.z * wv; acc[3] += x0.w * wv;
    acc[4] += x1.x * wv; acc[5] += x1.y * wv; acc[6] += x1.z * wv; acc[7] += x1.w * wv;
    acc[8] += x2.x * wv; acc[9] += x2.y * wv; acc[10] += x2.z * wv; acc[11] += x2.w * wv;
    acc[12] += x3.x * wv; acc[13] += x3.y * wv; acc[14] += x3.z * wv; acc[15] += x3.w * wv;
  }
  int head = c >> 6;
  float asv = as1[c];  // flat [head][c&63] == c
  float adv = ad1[c];
#pragma unroll
  for (int r = 0; r < 16; ++r) {
    h1[(base + r) * 256 + c] = acc[r];
    float vs = acc[r] * asv, vd = acc[r] * adv;
#pragma unroll
    for (int off = 32; off > 0; off >>= 1) {
      vs += __shfl_xor(vs, off);
      vd += __shfl_xor(vd, off);
    }
    if ((c & 63) == 0) {
      AS1[(base + r) * 4 + head] = vs;
      AD1[(base + r) * 4 + head] = vd;
    }
  }
}

// ---------------- GAT layer-1 aggregation: wave per node ----------------
__global__ __launch_bounds__(256) void k_agg1(
    const int* __restrict__ rp, const int* __restrict__ col,
    const float* __restrict__ h1, const float* __restrict__ AS1,
    const float* __restrict__ AD1, float* __restrict__ out) {
  int wave = threadIdx.x >> 6, lane = threadIdx.x & 63;
  int n = blockIdx.x * 4 + wave;
  int head = lane >> 4;
  int c4 = lane * 4;
  float adv = AD1[n * 4 + head];
  int e0 = rp[n], e1 = rp[n + 1];
  float ax = 0.f, ay = 0.f, az = 0.f, aw = 0.f, den = 0.f;
  for (int e = e0; e < e1; ++e) {
    int s = col[e];
    float ev = AS1[s * 4 + head] + adv;
    ev = ev > 0.f ? ev : NEG * ev;
    float p = __expf(ev);
    float4 hv = *(const float4*)(h1 + s * 256 + c4);
    ax += p * hv.x; ay += p * hv.y; az += p * hv.z; aw += p * hv.w;
    den += p;
  }
  float inv = 1.f / den;
  float4 o; o.x = ax * inv; o.y = ay * inv; o.z = az * inv; o.w = aw * inv;
  *(float4*)(out + n * 256 + c4) = o;
}

// ---------------- bias + ELU ----------------
__global__ void k_elu1(float* __restrict__ h, const float* __restrict__ b) {
  int i = blockIdx.x * 256 + threadIdx.x;  // NN*256 exact
  float v = h[i] + b[i & 255];
  h[i] = v > 0.f ? v : __expf(v) - 1.f;
}

__global__ void k_elu2(float* __restrict__ h, const float* __restrict__ b) {
  int i = blockIdx.x * 256 + threadIdx.x;  // NN*64 exact
  float v = h[i] + b[i & 63];
  h[i] = v > 0.f ? v : __expf(v) - 1.f;
}

// ---------------- GEMM2: h2 = h1act @ W2  [20000,256]x[256,64], + alphas ----------------
__global__ __launch_bounds__(256) void k_gemm2(
    const float* __restrict__ h1a, const float* __restrict__ W2,
    const float* __restrict__ as2, const float* __restrict__ ad2,
    float* __restrict__ h2, float* __restrict__ AS2, float* __restrict__ AD2) {
  __shared__ float xsT[256][20];
  int tid = threadIdx.x;
  int c = tid & 63, w = tid >> 6;  // wave w handles rows 4w..4w+3
  int base = blockIdx.x * 16;
  for (int i = tid; i < 16 * 256; i += 256) {
    int r = i >> 8, k = i & 255;
    xsT[k][r] = h1a[(base + r) * 256 + k];
  }
  __syncthreads();
  float acc[4] = {0.f, 0.f, 0.f, 0.f};
#pragma unroll 2
  for (int k = 0; k < 256; ++k) {
    float wv = W2[k * 64 + c];
    float4 xv = *(const float4*)&xsT[k][w * 4];
    acc[0] += xv.x * wv; acc[1] += xv.y * wv; acc[2] += xv.z * wv; acc[3] += xv.w * wv;
  }
  float asv = as2[c], adv = ad2[c];
#pragma unroll
  for (int rr = 0; rr < 4; ++rr) {
    int row = base + w * 4 + rr;
    h2[row * 64 + c] = acc[rr];
    float vs = acc[rr] * asv, vd = acc[rr] * adv;
#pragma unroll
    for (int off = 32; off > 0; off >>= 1) {
      vs += __shfl_xor(vs, off);
      vd += __shfl_xor(vd, off);
    }
    if (c == 0) { AS2[row] = vs; AD2[row] = vd; }
  }
}

// ---------------- GAT layer-2 aggregation ----------------
__global__ __launch_bounds__(256) void k_agg2(
    const int* __restrict__ rp, const int* __restrict__ col,
    const float* __restrict__ h2, const float* __restrict__ AS2,
    const float* __restrict__ AD2, float* __restrict__ out) {
  int wave = threadIdx.x >> 6, lane = threadIdx.x & 63;
  int n = blockIdx.x * 4 + wave;
  float adv = AD2[n];
  int e0 = rp[n], e1 = rp[n + 1];
  float acc = 0.f, den = 0.f;
  for (int e = e0; e < e1; ++e) {
    int s = col[e];
    float ev = AS2[s] + adv;
    ev = ev > 0.f ? ev : NEG * ev;
    float p = __expf(ev);
    acc += p * h2[s * 64 + lane];
    den += p;
  }
  out[n * 64 + lane] = acc / den;
}

// ---------------- weight prep: transpose Wp1, pad Wp2/bp2 to 88 cols ----------------
__global__ void k_prep(const float* __restrict__ Wp1, const float* __restrict__ Wp2,
                       const float* __restrict__ bp2, float* __restrict__ Wp1T,
                       float* __restrict__ Wp2p, float* __restrict__ bp2p) {
  int i = blockIdx.x * 256 + threadIdx.x;
  if (i < 128 * 64) { int r = i >> 6, cc = i & 63; Wp1T[cc * 128 + r] = Wp1[i]; }
  if (i < 64 * 88) { int t = i / 88, o = i % 88; Wp2p[i] = (o < 86) ? Wp2[t * 86 + o] : 0.f; }
  if (i < 88) bp2p[i] = (i < 86) ? bp2[i] : 0.f;
}

// ---------------- pair MLP: lane owns one pair-row; weights via scalar loads ----------------
__global__ __launch_bounds__(256) void k_pairs(
    const int* __restrict__ pairs, const float* __restrict__ h2a,
    const float* __restrict__ Wp1T, const float* __restrict__ bp1,
    const float* __restrict__ Wp2p, const float* __restrict__ bp2p,
    float* __restrict__ out) {
  int p = blockIdx.x * 256 + threadIdx.x;
  bool act = p < NP;
  int pclamped = act ? p : 0;
  int pi = pairs[2 * pclamped], pj = pairs[2 * pclamped + 1];
  const float* rowi = h2a + pi * 64;
  const float* rowj = h2a + pj * 64;

  float z[64];
#pragma unroll
  for (int t = 0; t < 64; ++t) z[t] = bp1[t];

  // z = relu(comb @ Wp1 + bp1); comb = [h2a[i], h2a[j]] (128)
  for (int kc = 0; kc < 8; ++kc) {  // runtime loop: 8 chunks of 16 k's
    const float* src = (kc < 4) ? rowi : rowj;
    int off = (kc & 3) * 16;
    float ck[16];
#pragma unroll
    for (int q = 0; q < 4; ++q) {
      float4 v = *(const float4*)(src + off + q * 4);
      ck[q * 4] = v.x; ck[q * 4 + 1] = v.y; ck[q * 4 + 2] = v.z; ck[q * 4 + 3] = v.w;
    }
    int k0 = kc * 16;
#pragma unroll
    for (int tt = 0; tt < 4; ++tt)
#pragma unroll
      for (int kk = 0; kk < 16; ++kk)
#pragma unroll
        for (int u = 0; u < 16; ++u)
          z[tt * 16 + u] += ck[kk] * Wp1T[(tt * 16 + u) * 128 + k0 + kk];
  }
#pragma unroll
  for (int t = 0; t < 64; ++t) z[t] = fmaxf(z[t], 0.f);

  // out = z @ Wp2 + bp2, 4 column chunks of 22 (padded to 88)
  for (int q = 0; q < 4; ++q) {  // runtime loop
    int o0 = q * 22;
    float acc[22];
#pragma unroll
    for (int j = 0; j < 22; ++j) acc[j] = bp2p[o0 + j];
#pragma unroll
    for (int t = 0; t < 64; ++t)
#pragma unroll
      for (int j = 0; j < 22; ++j)
        acc[j] += z[t] * Wp2p[t * 88 + o0 + j];
    if (act) {
#pragma unroll
      for (int j = 0; j < 22; ++j) {
        int o = o0 + j;
        if (o < 86) out[p * 86 + o] = acc[j];
      }
    }
  }
}

extern "C" void kernel_launch(void* const* d_in, const int* in_sizes, int n_in,
                              void* d_out, int out_size, void* d_ws, size_t ws_size,
                              hipStream_t stream) {
  (void)in_sizes; (void)n_in; (void)out_size; (void)ws_size;
  const float* x      = (const float*)d_in[0];
  const int*   ei     = (const int*)d_in[1];
  const int*   pairs  = (const int*)d_in[2];
  const float* W1     = (const float*)d_in[3];
  const float* a_src1 = (const float*)d_in[4];
  const float* a_dst1 = (const float*)d_in[5];
  const float* b1     = (const float*)d_in[6];
  const float* W2     = (const float*)d_in[7];
  const float* a_src2 = (const float*)d_in[8];
  const float* a_dst2 = (const float*)d_in[9];
  const float* b2     = (const float*)d_in[10];
  const float* Wp1    = (const float*)d_in[11];
  const float* bp1    = (const float*)d_in[12];
  const float* Wp2    = (const float*)d_in[13];
  const float* bp2    = (const float*)d_in[14];
  float* out = (float*)d_out;

  char* w = (char*)d_ws;
  auto alloc = [&](size_t bytes) -> void* {
    void* pp = (void*)w;
    w += (bytes + 255) & ~(size_t)255;
    return pp;
  };
  float* h1    = (float*)alloc((size_t)NN * 256 * 4);
  float* AS1   = (float*)alloc((size_t)NN * 4 * 4);
  float* AD1   = (float*)alloc((size_t)NN * 4 * 4);
  float* h1agg = (float*)alloc((size_t)NN * 256 * 4);
  float* h2    = (float*)alloc((size_t)NN * 64 * 4);
  float* AS2   = (float*)alloc((size_t)NN * 4);
  float* AD2   = (float*)alloc((size_t)NN * 4);
  float* h2agg = (float*)alloc((size_t)NN * 64 * 4);
  float* Wp1T  = (float*)alloc(64 * 128 * 4);
  float* Wp2p  = (float*)alloc(64 * 88 * 4);
  float* bp2p  = (float*)alloc(88 * 4);
  int*   rp    = (int*)alloc((size_t)(NN + 1) * 4);
  int*   cnt   = (int*)alloc((size_t)NN * 4);
  int*   cur   = (int*)alloc((size_t)NN * 4);
  int*   col   = (int*)alloc((size_t)NEE * 4);

  hipMemsetAsync(cnt, 0, (size_t)NN * 4, stream);
  hipMemsetAsync(cur, 0, (size_t)NN * 4, stream);

  const int EB = (NEE + 255) / 256;  // 2579
  k_hist<<<EB, 256, 0, stream>>>(ei, cnt);
  k_scan<<<1, 256, 0, stream>>>(cnt, rp);
  k_scatter<<<EB, 256, 0, stream>>>(ei, rp, cur, col);
  k_prep<<<32, 256, 0, stream>>>(Wp1, Wp2, bp2, Wp1T, Wp2p, bp2p);

  k_gemm1<<<NN / 16, 256, 0, stream>>>(x, W1, a_src1, a_dst1, h1, AS1, AD1);
  k_agg1<<<NN / 4, 256, 0, stream>>>(rp, col, h1, AS1, AD1, h1agg);
  k_elu1<<<NN * 256 / 256, 256, 0, stream>>>(h1agg, b1);

  k_gemm2<<<NN / 16, 256, 0, stream>>>(h1agg, W2, a_src2, a_dst2, h2, AS2, AD2);
  k_agg2<<<NN / 4, 256, 0, stream>>>(rp, col, h2, AS2, AD2, h2agg);
  k_elu2<<<NN * 64 / 256, 256, 0, stream>>>(h2agg, b2);

  k_pairs<<<(NP + 255) / 256, 256, 0, stream>>>(pairs, h2agg, Wp1T, bp1, Wp2p, bp2p, out);
}